// Round 5
// baseline (123.075 us; speedup 1.0000x reference)
//
#include <hip/hip_runtime.h>
#include <math.h>

// Problem constants
#define BB 32
#define TT 4096
#define DD 512
#define SS 256
#define NCH 128           // chunks per batch
#define CR 32             // rows per chunk (NCH*CR == TT)
static constexpr float INV_SCALE = 10.0f;   // 1/0.1

// ---------------------------------------------------------------------------
// Kernel 1: q = silu(t_star*W1+b1) @ W2 + b2.
// grid = B*8 blocks (b, jg); block 512 = 64 outputs x 8 k-groups.
// ---------------------------------------------------------------------------
__global__ __launch_bounds__(512) void k_q(
    const float* __restrict__ t_star, const float* __restrict__ W1,
    const float* __restrict__ b1, const float* __restrict__ W2,
    const float* __restrict__ b2, float* __restrict__ q) {
  const int b   = blockIdx.x >> 3;
  const int jg  = blockIdx.x & 7;
  const int tid = threadIdx.x;
  const int di  = tid & 63;
  const int kg  = tid >> 6;
  __shared__ float h[DD];
  __shared__ float red[8][64];
  {
    float x = t_star[b] * W1[tid] + b1[tid];
    h[tid] = x / (1.0f + __expf(-x));     // silu
  }
  __syncthreads();
  const float* w = W2 + jg * 64 + di;
  float acc = 0.0f;
#pragma unroll 8
  for (int kk = 0; kk < 64; ++kk) {
    const int k = kg * 64 + kk;
    acc += h[k] * w[(size_t)k * DD];
  }
  red[kg][di] = acc;
  __syncthreads();
  if (tid < 64) {
    float s = 0.0f;
#pragma unroll
    for (int g = 0; g < 8; ++g) s += red[g][tid];
    q[b * DD + jg * 64 + tid] = s + b2[jg * 64 + tid];
  }
}

// ---------------------------------------------------------------------------
// Kernel 2: wave-independent flash pooling, 32-row chunks, 4-row groups,
// double-buffered. VGPR-lean (~110) so __launch_bounds__(256,4) holds
// 16 waves/CU. No LDS, no __syncthreads.
// ---------------------------------------------------------------------------
__device__ __forceinline__ void load_g(
    const float* cbase, int g, int lane, float4 (&d0)[4], float4 (&d1)[4]) {
  const float4* cp = (const float4*)(cbase + (size_t)g * 4 * DD);
#pragma unroll
  for (int r = 0; r < 4; ++r) {
    d0[r] = cp[r * 128 + lane];
    d1[r] = cp[r * 128 + 64 + lane];
  }
}

__device__ __forceinline__ void comp_g(
    const float4 (&d0)[4], const float4 (&d1)[4], int g,
    const float4 q0, const float4 q1, float tb,
    float& m, float& l, float4& p0, float4& p1) {
  float s[4];
#pragma unroll
  for (int r = 0; r < 4; ++r) {
    float a = d0[r].x * q0.x + d0[r].y * q0.y + d0[r].z * q0.z + d0[r].w * q0.w +
              d1[r].x * q1.x + d1[r].y * q1.y + d1[r].z * q1.z + d1[r].w * q1.w;
#pragma unroll
    for (int off = 32; off > 0; off >>= 1) a += __shfl_xor(a, off);
    s[r] = a + __shfl(tb, g * 4 + r);
  }
  const float gm = fmaxf(fmaxf(s[0], s[1]), fmaxf(s[2], s[3]));
  const float nm = fmaxf(m, gm);
  const float sc = __expf(m - nm);   // first group: exp(-inf)=0, p==0 anyway
  m = nm;
  l *= sc;
  p0.x *= sc; p0.y *= sc; p0.z *= sc; p0.w *= sc;
  p1.x *= sc; p1.y *= sc; p1.z *= sc; p1.w *= sc;
#pragma unroll
  for (int r = 0; r < 4; ++r) {
    const float e = __expf(s[r] - m);
    l += e;
    p0.x += e * d0[r].x; p0.y += e * d0[r].y;
    p0.z += e * d0[r].z; p0.w += e * d0[r].w;
    p1.x += e * d1[r].x; p1.y += e * d1[r].y;
    p1.z += e * d1[r].z; p1.w += e * d1[r].w;
  }
}

__global__ __launch_bounds__(256, 4) void k_fused(
    const float* __restrict__ ctx, const float* __restrict__ q,
    const float* __restrict__ t_star, const float* __restrict__ t_ctx,
    float* __restrict__ part_pool,    // [B*NCH*DD]
    float* __restrict__ part_ms) {    // [B*NCH*2]  (m_c, l_c)
  const int wid  = threadIdx.x >> 6;
  const int lane = threadIdx.x & 63;
  const int wg   = blockIdx.x * 4 + wid;   // global wave id
  const int b    = wg >> 7;                // / NCH
  const int c    = wg & 127;               // % NCH

  const float4* qp = (const float4*)(q + b * DD);
  const float4 q0 = qp[lane];
  const float4 q1 = qp[64 + lane];
  const float ts = t_star[b];
  const float tb = -fabsf(ts - t_ctx[b * TT + c * CR + (lane & 31)]) * INV_SCALE;

  const float* cbase = ctx + ((size_t)b * TT + (size_t)c * CR) * DD;

  float m = -INFINITY, l = 0.0f;
  float4 p0 = {0, 0, 0, 0}, p1 = {0, 0, 0, 0};

  float4 A0[4], A1[4], B0[4], B1[4];
  load_g(cbase, 0, lane, A0, A1);
  load_g(cbase, 1, lane, B0, B1);
  comp_g(A0, A1, 0, q0, q1, tb, m, l, p0, p1);
  load_g(cbase, 2, lane, A0, A1);
  comp_g(B0, B1, 1, q0, q1, tb, m, l, p0, p1);
  load_g(cbase, 3, lane, B0, B1);
  comp_g(A0, A1, 2, q0, q1, tb, m, l, p0, p1);
  load_g(cbase, 4, lane, A0, A1);
  comp_g(B0, B1, 3, q0, q1, tb, m, l, p0, p1);
  load_g(cbase, 5, lane, B0, B1);
  comp_g(A0, A1, 4, q0, q1, tb, m, l, p0, p1);
  load_g(cbase, 6, lane, A0, A1);
  comp_g(B0, B1, 5, q0, q1, tb, m, l, p0, p1);
  load_g(cbase, 7, lane, B0, B1);
  comp_g(A0, A1, 6, q0, q1, tb, m, l, p0, p1);
  comp_g(B0, B1, 7, q0, q1, tb, m, l, p0, p1);

  float4* pp = (float4*)(part_pool + ((size_t)b * NCH + c) * DD);
  pp[lane] = p0;
  pp[64 + lane] = p1;
  if (lane == 0) {
    part_ms[(b * NCH + c) * 2 + 0] = m;
    part_ms[(b * NCH + c) * 2 + 1] = l;
  }
}

// ---------------------------------------------------------------------------
// Kernel 3: merge chunk partials into pool[b,:] (normalized).
// grid = B*4 (b, dg); block 512 = 128 d x 4 cg. Each thread sums 32 chunks.
// ---------------------------------------------------------------------------
__global__ __launch_bounds__(512) void k_merge(
    const float* __restrict__ part_pool, const float* __restrict__ part_ms,
    float* __restrict__ pool) {
  const int b  = blockIdx.x >> 2;
  const int dg = blockIdx.x & 3;
  const int tid = threadIdx.x;
  const int dl = tid & 127;
  const int cg = tid >> 7;
  const int lane = tid & 63;
  const int bN = b * NCH;
  __shared__ float scl[NCH];
  __shared__ float red[4][128];

  // wave-parallel M and Z over 128 chunks (each wave redundantly)
  float mA = part_ms[(bN + lane) * 2 + 0];
  float mB = part_ms[(bN + 64 + lane) * 2 + 0];
  float lA = part_ms[(bN + lane) * 2 + 1];
  float lB = part_ms[(bN + 64 + lane) * 2 + 1];
  float M = fmaxf(mA, mB);
#pragma unroll
  for (int off = 32; off > 0; off >>= 1) M = fmaxf(M, __shfl_xor(M, off));
  float Z = __expf(mA - M) * lA + __expf(mB - M) * lB;
#pragma unroll
  for (int off = 32; off > 0; off >>= 1) Z += __shfl_xor(Z, off);
  const float invZ = 1.0f / Z;
  if (tid < NCH) scl[tid] = __expf(part_ms[(bN + tid) * 2] - M);
  __syncthreads();

  const int d = dg * 128 + dl;
  float acc = 0.0f;
#pragma unroll 8
  for (int i = 0; i < 32; ++i) {
    const int c = cg * 32 + i;
    acc += scl[c] * part_pool[((size_t)bN + c) * DD + d];
  }
  red[cg][dl] = acc;
  __syncthreads();
  if (tid < 128) {
    float s = red[0][tid] + red[1][tid] + red[2][tid] + red[3][tid];
    pool[b * DD + dg * 128 + tid] = s * invZ;
  }
}

// ---------------------------------------------------------------------------
// Kernel 4: out = pool @ Wout + bout. grid = B*8 (b,jg); block 256 = 4 kg x 64 j.
// ---------------------------------------------------------------------------
__global__ __launch_bounds__(256) void k_out(
    const float* __restrict__ pool, const float* __restrict__ Wout,
    const float* __restrict__ bout, float* __restrict__ out) {
  const int b   = blockIdx.x >> 3;
  const int jg  = blockIdx.x & 7;
  const int tid = threadIdx.x;
  const int kg  = tid >> 6;
  const int j   = tid & 63;
  const int jc  = jg * 64 + j;
  __shared__ float p[DD];
  __shared__ float red[4][64];

  p[tid] = pool[b * DD + tid];
  p[tid + 256] = pool[b * DD + 256 + tid];
  __syncthreads();

  float acc = 0.0f;
#pragma unroll 8
  for (int kk = 0; kk < 128; ++kk) {
    const int k = kg * 128 + kk;
    acc += p[k] * Wout[(size_t)k * DD + jc];
  }
  red[kg][j] = acc;
  __syncthreads();
  if (tid < 64) {
    const int jj = jg * 64 + tid;
    float o = red[0][tid] + red[1][tid] + red[2][tid] + red[3][tid] + bout[jj];
    if (jj < SS) out[b * SS + jj] = o;                       // mu
    else         out[BB * SS + b * SS + (jj - SS)] = o;      // log_sigma
  }
}

// ---------------------------------------------------------------------------
extern "C" void kernel_launch(void* const* d_in, const int* in_sizes, int n_in,
                              void* d_out, int out_size, void* d_ws, size_t ws_size,
                              hipStream_t stream) {
  const float* ctx    = (const float*)d_in[0];   // (B,T,D)
  const float* t_star = (const float*)d_in[1];   // (B,)
  const float* t_ctx  = (const float*)d_in[2];   // (B,T,1)
  const float* W1     = (const float*)d_in[3];   // (1,D)
  const float* b1     = (const float*)d_in[4];   // (D,)
  const float* W2     = (const float*)d_in[5];   // (D,D)
  const float* b2     = (const float*)d_in[6];   // (D,)
  const float* Wout   = (const float*)d_in[7];   // (D,2S)
  const float* bout   = (const float*)d_in[8];   // (2S,)
  float* out = (float*)d_out;

  float* ws = (float*)d_ws;
  float* q         = ws;                                   // B*D
  float* part_pool = q + (size_t)BB * DD;                  // B*NCH*D  (8 MB)
  float* part_ms   = part_pool + (size_t)BB * NCH * DD;    // B*NCH*2
  float* pool      = part_ms + (size_t)BB * NCH * 2;       // B*D

  k_q<<<BB * 8, 512, 0, stream>>>(t_star, W1, b1, W2, b2, q);
  k_fused<<<BB * NCH / 4, 256, 0, stream>>>(ctx, q, t_star, t_ctx, part_pool, part_ms);
  k_merge<<<BB * 4, 512, 0, stream>>>(part_pool, part_ms, pool);
  k_out<<<BB * 8, 256, 0, stream>>>(pool, Wout, bout, out);
}

// Round 6
// 80.220 us; speedup vs baseline: 1.5342x; 1.5342x over previous
//
#include <hip/hip_runtime.h>
#include <math.h>

// Problem constants
#define BB 32
#define TT 4096
#define DD 512
#define SS 256
#define SEG 128           // wave-segments per batch (each wave: 32 rows)
#define GRP 16            // groups of 2 rows per wave (GRP*2*SEG == TT)
static constexpr float INV_SCALE = 10.0f;   // 1/0.1

// ---------------------------------------------------------------------------
// Kernel 1: q = silu(t_star*W1+b1) @ W2 + b2.
// grid = B*8 blocks (b, jg); block 512 = 64 outputs x 8 k-groups.
// ---------------------------------------------------------------------------
__global__ __launch_bounds__(512) void k_q(
    const float* __restrict__ t_star, const float* __restrict__ W1,
    const float* __restrict__ b1, const float* __restrict__ W2,
    const float* __restrict__ b2, float* __restrict__ q) {
  const int b   = blockIdx.x >> 3;
  const int jg  = blockIdx.x & 7;
  const int tid = threadIdx.x;
  const int di  = tid & 63;
  const int kg  = tid >> 6;
  __shared__ float h[DD];
  __shared__ float red[8][64];
  {
    float x = t_star[b] * W1[tid] + b1[tid];
    h[tid] = x / (1.0f + __expf(-x));     // silu
  }
  __syncthreads();
  const float* w = W2 + jg * 64 + di;
  float acc = 0.0f;
#pragma unroll 8
  for (int kk = 0; kk < 64; ++kk) {
    const int k = kg * 64 + kk;
    acc += h[k] * w[(size_t)k * DD];
  }
  red[kg][di] = acc;
  __syncthreads();
  if (tid < 64) {
    float s = 0.0f;
#pragma unroll
    for (int g = 0; g < 8; ++g) s += red[g][tid];
    q[b * DD + jg * 64 + tid] = s + b2[jg * 64 + tid];
  }
}

// ---------------------------------------------------------------------------
// Kernel 2: LDS-staged flash pooling. Each WAVE owns 32 rows (one segment),
// processed as 16 groups of 2 rows via a 2-slot LDS ring filled by
// global_load_lds (width 16). Counted s_waitcnt vmcnt(4) keeps the next
// group's 4 loads in flight across the compute. Per-wave online (m,l,p);
// NO __syncthreads, no cross-wave LDS sharing.
// Row mapping r = 2*(g*SEG+s): at each step g, the 128 waves of a batch
// read a contiguous 256-row address front (coherent stream sweep).
// ---------------------------------------------------------------------------
#define GLDS(gp, lp)                                                        \
  __builtin_amdgcn_global_load_lds(                                         \
      (const __attribute__((address_space(1))) void*)(gp),                  \
      (__attribute__((address_space(3))) void*)(lp), 16, 0, 0)

__global__ __launch_bounds__(256) void k_fused(
    const float* __restrict__ ctx, const float* __restrict__ q,
    const float* __restrict__ t_star, const float* __restrict__ t_ctx,
    float* __restrict__ part_pool,    // [B*SEG*DD]
    float* __restrict__ part_ms) {    // [B*SEG*2]  (m, l)
  __shared__ __align__(16) float lds[4][2][2 * DD];   // [wave][slot][2 rows]
  const int wid  = threadIdx.x >> 6;
  const int lane = threadIdx.x & 63;
  const int w    = blockIdx.x * 4 + wid;   // global wave id
  const int b    = w >> 7;                 // / SEG
  const int s    = w & 127;                // % SEG

  const float4* qp = (const float4*)(q + b * DD);
  const float4 q0 = qp[lane];
  const float4 q1 = qp[64 + lane];
  const float ts = t_star[b];
  // lane g (g<16) holds the time-bias pair for its group's rows
  const float2 tc = *(const float2*)(t_ctx + b * TT + ((lane & 15) * 2 * SEG + 2 * s));
  const float tbx = -fabsf(ts - tc.x) * INV_SCALE;
  const float tby = -fabsf(ts - tc.y) * INV_SCALE;

  float m = -INFINITY, l = 0.0f;
  float4 p0 = {0, 0, 0, 0}, p1 = {0, 0, 0, 0};

  const float* cb = ctx + ((size_t)b * TT + 2 * s) * DD;   // group-0 base

  // prologue: stage group 0 into slot 0
  {
    const float* gb = cb;
    float* sb = &lds[wid][0][0];
#pragma unroll
    for (int piece = 0; piece < 4; ++piece)
      GLDS(gb + piece * 256 + lane * 4, sb + piece * 256);
  }

#pragma unroll
  for (int g = 0; g < GRP; ++g) {
    if (g + 1 < GRP) {
      // stage group g+1 into the other slot (4 x 1KB fire-and-forget)
      const float* gb = cb + (size_t)(g + 1) * 2 * SEG * DD;
      float* sb = &lds[wid][(g + 1) & 1][0];
#pragma unroll
      for (int piece = 0; piece < 4; ++piece)
        GLDS(gb + piece * 256 + lane * 4, sb + piece * 256);
      asm volatile("s_waitcnt vmcnt(4)" ::: "memory");   // group g resident
    } else {
      asm volatile("s_waitcnt vmcnt(0)" ::: "memory");
    }

    const float4* sf = (const float4*)&lds[wid][g & 1][0];
    const float4 x0 = sf[lane];        // row0 dims [lane*4 .. +3]
    const float4 x1 = sf[64 + lane];   // row0 dims [256+lane*4 ..]
    const float4 y0 = sf[128 + lane];  // row1
    const float4 y1 = sf[192 + lane];

    float s0 = x0.x * q0.x + x0.y * q0.y + x0.z * q0.z + x0.w * q0.w +
               x1.x * q1.x + x1.y * q1.y + x1.z * q1.z + x1.w * q1.w;
    float s1 = y0.x * q0.x + y0.y * q0.y + y0.z * q0.z + y0.w * q0.w +
               y1.x * q1.x + y1.y * q1.y + y1.z * q1.z + y1.w * q1.w;
#pragma unroll
    for (int off = 32; off > 0; off >>= 1) {
      s0 += __shfl_xor(s0, off);
      s1 += __shfl_xor(s1, off);
    }
    s0 += __shfl(tbx, g);
    s1 += __shfl(tby, g);

    const float gm = fmaxf(s0, s1);
    const float nm = fmaxf(m, gm);
    const float sc = __expf(m - nm);   // g==0: exp(-inf)=0, p=l=0 anyway
    m = nm;
    const float e0 = __expf(s0 - m);
    const float e1 = __expf(s1 - m);
    l = l * sc + e0 + e1;
    p0.x = p0.x * sc + e0 * x0.x + e1 * y0.x;
    p0.y = p0.y * sc + e0 * x0.y + e1 * y0.y;
    p0.z = p0.z * sc + e0 * x0.z + e1 * y0.z;
    p0.w = p0.w * sc + e0 * x0.w + e1 * y0.w;
    p1.x = p1.x * sc + e0 * x1.x + e1 * y1.x;
    p1.y = p1.y * sc + e0 * x1.y + e1 * y1.y;
    p1.z = p1.z * sc + e0 * x1.z + e1 * y1.z;
    p1.w = p1.w * sc + e0 * x1.w + e1 * y1.w;
  }

  float4* pp = (float4*)(part_pool + (size_t)w * DD);
  pp[lane] = p0;
  pp[64 + lane] = p1;
  if (lane == 0) {
    part_ms[w * 2 + 0] = m;
    part_ms[w * 2 + 1] = l;
  }
}

// ---------------------------------------------------------------------------
// Kernel 3: merge segment partials (exact online-softmax) + Wout epilogue.
// grid = B*8 (b, jg); block 256.
// ---------------------------------------------------------------------------
__global__ __launch_bounds__(256) void k_final(
    const float* __restrict__ part_pool, const float* __restrict__ part_ms,
    const float* __restrict__ Wout, const float* __restrict__ bout,
    float* __restrict__ out) {
  const int b   = blockIdx.x >> 3;
  const int jg  = blockIdx.x & 7;
  const int tid = threadIdx.x;
  const int lane = tid & 63;
  __shared__ float scl[SEG];
  __shared__ float pool_s[DD];
  __shared__ float red[4][64];
  const int base = b * SEG;

  // wave-parallel global (M, Z) over 128 segments (each wave redundantly)
  const float mA = part_ms[(base + lane) * 2 + 0];
  const float mB = part_ms[(base + 64 + lane) * 2 + 0];
  const float lA = part_ms[(base + lane) * 2 + 1];
  const float lB = part_ms[(base + 64 + lane) * 2 + 1];
  float M = fmaxf(mA, mB);
#pragma unroll
  for (int off = 32; off > 0; off >>= 1) M = fmaxf(M, __shfl_xor(M, off));
  float Z = __expf(mA - M) * lA + __expf(mB - M) * lB;
#pragma unroll
  for (int off = 32; off > 0; off >>= 1) Z += __shfl_xor(Z, off);
  const float invZ = 1.0f / Z;
  if (tid < SEG) scl[tid] = __expf(part_ms[(base + tid) * 2] - M);
  __syncthreads();

  for (int d = tid; d < DD; d += 256) {
    float acc = 0.0f;
#pragma unroll 8
    for (int c = 0; c < SEG; ++c)
      acc += scl[c] * part_pool[((size_t)base + c) * DD + d];
    pool_s[d] = acc * invZ;
  }
  __syncthreads();

  const int kg = tid >> 6;
  const int j  = tid & 63;
  const int jc = jg * 64 + j;
  float acc = 0.0f;
#pragma unroll 8
  for (int kk = 0; kk < 128; ++kk) {
    const int k = kg * 128 + kk;
    acc += pool_s[k] * Wout[(size_t)k * DD + jc];
  }
  red[kg][j] = acc;
  __syncthreads();
  if (tid < 64) {
    const int jj = jg * 64 + tid;
    float o = red[0][tid] + red[1][tid] + red[2][tid] + red[3][tid] + bout[jj];
    if (jj < SS) out[b * SS + jj] = o;                       // mu
    else         out[BB * SS + b * SS + (jj - SS)] = o;      // log_sigma
  }
}

// ---------------------------------------------------------------------------
extern "C" void kernel_launch(void* const* d_in, const int* in_sizes, int n_in,
                              void* d_out, int out_size, void* d_ws, size_t ws_size,
                              hipStream_t stream) {
  const float* ctx    = (const float*)d_in[0];   // (B,T,D)
  const float* t_star = (const float*)d_in[1];   // (B,)
  const float* t_ctx  = (const float*)d_in[2];   // (B,T,1)
  const float* W1     = (const float*)d_in[3];   // (1,D)
  const float* b1     = (const float*)d_in[4];   // (D,)
  const float* W2     = (const float*)d_in[5];   // (D,D)
  const float* b2     = (const float*)d_in[6];   // (D,)
  const float* Wout   = (const float*)d_in[7];   // (D,2S)
  const float* bout   = (const float*)d_in[8];   // (2S,)
  float* out = (float*)d_out;

  float* ws = (float*)d_ws;
  float* q         = ws;                                   // B*D
  float* part_pool = q + (size_t)BB * DD;                  // B*SEG*D  (8 MB)
  float* part_ms   = part_pool + (size_t)BB * SEG * DD;    // B*SEG*2

  k_q<<<BB * 8, 512, 0, stream>>>(t_star, W1, b1, W2, b2, q);
  k_fused<<<BB * SEG / 4, 256, 0, stream>>>(ctx, q, t_star, t_ctx, part_pool, part_ms);
  k_final<<<BB * 8, 256, 0, stream>>>(part_pool, part_ms, Wout, bout, out);
}

// Round 7
// 73.123 us; speedup vs baseline: 1.6831x; 1.0971x over previous
//
#include <hip/hip_runtime.h>
#include <math.h>

// Problem constants
#define BB 32
#define TT 4096
#define DD 512
#define SS 256
#define SEG 128           // wave-segments per batch (each wave: 32 rows)
#define GRP 16            // groups of 2 rows per wave (GRP*2*SEG == TT)
static constexpr float INV_SCALE = 10.0f;   // 1/0.1

// ---------------------------------------------------------------------------
// Kernel 1: q = silu(t_star*W1+b1) @ W2 + b2.
// grid = B*8 blocks (b, jg); block 512 = 64 outputs x 8 k-groups.
// ---------------------------------------------------------------------------
__global__ __launch_bounds__(512) void k_q(
    const float* __restrict__ t_star, const float* __restrict__ W1,
    const float* __restrict__ b1, const float* __restrict__ W2,
    const float* __restrict__ b2, float* __restrict__ q) {
  const int b   = blockIdx.x >> 3;
  const int jg  = blockIdx.x & 7;
  const int tid = threadIdx.x;
  const int di  = tid & 63;
  const int kg  = tid >> 6;
  __shared__ float h[DD];
  __shared__ float red[8][64];
  {
    float x = t_star[b] * W1[tid] + b1[tid];
    h[tid] = x / (1.0f + __expf(-x));     // silu
  }
  __syncthreads();
  const float* w = W2 + jg * 64 + di;
  float acc = 0.0f;
#pragma unroll 8
  for (int kk = 0; kk < 64; ++kk) {
    const int k = kg * 64 + kk;
    acc += h[k] * w[(size_t)k * DD];
  }
  red[kg][di] = acc;
  __syncthreads();
  if (tid < 64) {
    float s = 0.0f;
#pragma unroll
    for (int g = 0; g < 8; ++g) s += red[g][tid];
    q[b * DD + jg * 64 + tid] = s + b2[jg * 64 + tid];
  }
}

// ---------------------------------------------------------------------------
// Kernel 2: LDS-staged flash pooling, depth-2 prefetch (3-slot ring).
// Each WAVE owns 32 rows; 16 groups of 2 rows. Per iteration: issue group
// g+2's 4 global_load_lds, s_waitcnt vmcnt(8) (g+1,g+2 stay in flight),
// consume group g from LDS. No __syncthreads, no cross-wave sharing.
// ---------------------------------------------------------------------------
#define GLDS(gp, lp)                                                        \
  __builtin_amdgcn_global_load_lds(                                         \
      (const __attribute__((address_space(1))) void*)(gp),                  \
      (__attribute__((address_space(3))) void*)(lp), 16, 0, 0)

__global__ __launch_bounds__(256) void k_fused(
    const float* __restrict__ ctx, const float* __restrict__ q,
    const float* __restrict__ t_star, const float* __restrict__ t_ctx,
    float* __restrict__ part_pool,    // [B*SEG*DD]
    float* __restrict__ part_ms) {    // [B*SEG*2]  (m, l)
  __shared__ __align__(16) float lds[4][3][2 * DD];   // 48 KB: [wave][slot][2 rows]
  const int wid  = threadIdx.x >> 6;
  const int lane = threadIdx.x & 63;
  const int w    = blockIdx.x * 4 + wid;   // global wave id
  const int b    = w >> 7;                 // / SEG
  const int s    = w & 127;                // % SEG

  const float4* qp = (const float4*)(q + b * DD);
  const float4 q0 = qp[lane];
  const float4 q1 = qp[64 + lane];
  const float ts = t_star[b];
  // lane g (g<16) holds the time-bias pair for its group's rows
  const float2 tc = *(const float2*)(t_ctx + b * TT + ((lane & 15) * 2 * SEG + 2 * s));
  const float tbx = -fabsf(ts - tc.x) * INV_SCALE;
  const float tby = -fabsf(ts - tc.y) * INV_SCALE;

  float m = -INFINITY, l = 0.0f;
  float4 p0 = {0, 0, 0, 0}, p1 = {0, 0, 0, 0};

  const float* cb = ctx + ((size_t)b * TT + 2 * s) * DD;   // group-0 base

  // prologue: stage groups 0,1 into slots 0,1
#pragma unroll
  for (int g = 0; g < 2; ++g) {
    const float* gb = cb + (size_t)g * 2 * SEG * DD;
    float* sb = &lds[wid][g][0];
#pragma unroll
    for (int piece = 0; piece < 4; ++piece)
      GLDS(gb + piece * 256 + lane * 4, sb + piece * 256);
  }

#pragma unroll
  for (int g = 0; g < GRP; ++g) {
    if (g + 2 < GRP) {
      const float* gb = cb + (size_t)(g + 2) * 2 * SEG * DD;
      float* sb = &lds[wid][(g + 2) % 3][0];
#pragma unroll
      for (int piece = 0; piece < 4; ++piece)
        GLDS(gb + piece * 256 + lane * 4, sb + piece * 256);
      asm volatile("s_waitcnt vmcnt(8)" ::: "memory");   // group g resident
    } else if (g + 1 < GRP) {
      asm volatile("s_waitcnt vmcnt(4)" ::: "memory");
    } else {
      asm volatile("s_waitcnt vmcnt(0)" ::: "memory");
    }

    const float4* sf = (const float4*)&lds[wid][g % 3][0];
    const float4 x0 = sf[lane];        // row0 dims [lane*4 .. +3]
    const float4 x1 = sf[64 + lane];   // row0 dims [256+lane*4 ..]
    const float4 y0 = sf[128 + lane];  // row1
    const float4 y1 = sf[192 + lane];

    float s0 = x0.x * q0.x + x0.y * q0.y + x0.z * q0.z + x0.w * q0.w +
               x1.x * q1.x + x1.y * q1.y + x1.z * q1.z + x1.w * q1.w;
    float s1 = y0.x * q0.x + y0.y * q0.y + y0.z * q0.z + y0.w * q0.w +
               y1.x * q1.x + y1.y * q1.y + y1.z * q1.z + y1.w * q1.w;
#pragma unroll
    for (int off = 32; off > 0; off >>= 1) {
      s0 += __shfl_xor(s0, off);
      s1 += __shfl_xor(s1, off);
    }
    s0 += __shfl(tbx, g);
    s1 += __shfl(tby, g);

    const float gm = fmaxf(s0, s1);
    const float nm = fmaxf(m, gm);
    const float sc = __expf(m - nm);   // g==0: exp(-inf)=0, p=l=0 anyway
    m = nm;
    const float e0 = __expf(s0 - m);
    const float e1 = __expf(s1 - m);
    l = l * sc + e0 + e1;
    p0.x = p0.x * sc + e0 * x0.x + e1 * y0.x;
    p0.y = p0.y * sc + e0 * x0.y + e1 * y0.y;
    p0.z = p0.z * sc + e0 * x0.z + e1 * y0.z;
    p0.w = p0.w * sc + e0 * x0.w + e1 * y0.w;
    p1.x = p1.x * sc + e0 * x1.x + e1 * y1.x;
    p1.y = p1.y * sc + e0 * x1.y + e1 * y1.y;
    p1.z = p1.z * sc + e0 * x1.z + e1 * y1.z;
    p1.w = p1.w * sc + e0 * x1.w + e1 * y1.w;
  }

  float4* pp = (float4*)(part_pool + (size_t)w * DD);
  pp[lane] = p0;
  pp[64 + lane] = p1;
  if (lane == 0) {
    part_ms[w * 2 + 0] = m;
    part_ms[w * 2 + 1] = l;
  }
}

// ---------------------------------------------------------------------------
// Kernel 3: merge segment partials into normalized pool[b,:].
// grid = B*4 (b, dg); block 512 = 128 d x 4 chunk-groups. part_pool read ONCE.
// ---------------------------------------------------------------------------
__global__ __launch_bounds__(512) void k_merge(
    const float* __restrict__ part_pool, const float* __restrict__ part_ms,
    float* __restrict__ pool) {
  const int b   = blockIdx.x >> 2;
  const int dg  = blockIdx.x & 3;
  const int tid = threadIdx.x;
  const int lane = tid & 63;
  const int base = b * SEG;
  __shared__ float scl[SEG];
  __shared__ float red[4][128];

  // wave-parallel global (M, Z) over 128 segments (each wave redundantly)
  const float mA = part_ms[(base + lane) * 2 + 0];
  const float mB = part_ms[(base + 64 + lane) * 2 + 0];
  const float lA = part_ms[(base + lane) * 2 + 1];
  const float lB = part_ms[(base + 64 + lane) * 2 + 1];
  float M = fmaxf(mA, mB);
#pragma unroll
  for (int off = 32; off > 0; off >>= 1) M = fmaxf(M, __shfl_xor(M, off));
  float Z = __expf(mA - M) * lA + __expf(mB - M) * lB;
#pragma unroll
  for (int off = 32; off > 0; off >>= 1) Z += __shfl_xor(Z, off);
  const float invZ = 1.0f / Z;
  if (tid < SEG) scl[tid] = __expf(part_ms[(base + tid) * 2] - M);
  __syncthreads();

  const int dl = tid & 127;
  const int cg = tid >> 7;
  float acc = 0.0f;
#pragma unroll 8
  for (int i = 0; i < 32; ++i) {
    const int c = cg * 32 + i;
    acc += scl[c] * part_pool[((size_t)base + c) * DD + dg * 128 + dl];
  }
  red[cg][dl] = acc;
  __syncthreads();
  if (tid < 128)
    pool[b * DD + dg * 128 + tid] =
        (red[0][tid] + red[1][tid] + red[2][tid] + red[3][tid]) * invZ;
}

// ---------------------------------------------------------------------------
// Kernel 4: out = pool @ Wout + bout. grid = B*8 (b,jg); block 256 = 4kg x 64j.
// ---------------------------------------------------------------------------
__global__ __launch_bounds__(256) void k_out(
    const float* __restrict__ pool, const float* __restrict__ Wout,
    const float* __restrict__ bout, float* __restrict__ out) {
  const int b   = blockIdx.x >> 3;
  const int jg  = blockIdx.x & 7;
  const int tid = threadIdx.x;
  const int kg  = tid >> 6;
  const int j   = tid & 63;
  const int jc  = jg * 64 + j;
  __shared__ float p[DD];
  __shared__ float red[4][64];

  p[tid] = pool[b * DD + tid];
  p[tid + 256] = pool[b * DD + 256 + tid];
  __syncthreads();

  float acc = 0.0f;
#pragma unroll 8
  for (int kk = 0; kk < 128; ++kk) {
    const int k = kg * 128 + kk;
    acc += p[k] * Wout[(size_t)k * DD + jc];
  }
  red[kg][j] = acc;
  __syncthreads();
  if (tid < 64) {
    const int jj = jg * 64 + tid;
    float o = red[0][tid] + red[1][tid] + red[2][tid] + red[3][tid] + bout[jj];
    if (jj < SS) out[b * SS + jj] = o;                       // mu
    else         out[BB * SS + b * SS + (jj - SS)] = o;      // log_sigma
  }
}

// ---------------------------------------------------------------------------
extern "C" void kernel_launch(void* const* d_in, const int* in_sizes, int n_in,
                              void* d_out, int out_size, void* d_ws, size_t ws_size,
                              hipStream_t stream) {
  const float* ctx    = (const float*)d_in[0];   // (B,T,D)
  const float* t_star = (const float*)d_in[1];   // (B,)
  const float* t_ctx  = (const float*)d_in[2];   // (B,T,1)
  const float* W1     = (const float*)d_in[3];   // (1,D)
  const float* b1     = (const float*)d_in[4];   // (D,)
  const float* W2     = (const float*)d_in[5];   // (D,D)
  const float* b2     = (const float*)d_in[6];   // (D,)
  const float* Wout   = (const float*)d_in[7];   // (D,2S)
  const float* bout   = (const float*)d_in[8];   // (2S,)
  float* out = (float*)d_out;

  float* ws = (float*)d_ws;
  float* q         = ws;                                   // B*D
  float* part_pool = q + (size_t)BB * DD;                  // B*SEG*D  (8 MB)
  float* part_ms   = part_pool + (size_t)BB * SEG * DD;    // B*SEG*2
  float* pool      = part_ms + (size_t)BB * SEG * 2;       // B*D

  k_q<<<BB * 8, 512, 0, stream>>>(t_star, W1, b1, W2, b2, q);
  k_fused<<<BB * SEG / 4, 256, 0, stream>>>(ctx, q, t_star, t_ctx, part_pool, part_ms);
  k_merge<<<BB * 4, 512, 0, stream>>>(part_pool, part_ms, pool);
  k_out<<<BB * 8, 256, 0, stream>>>(pool, Wout, bout, out);
}